// Round 15
// baseline (132.305 us; speedup 1.0000x reference)
//
#include <hip/hip_runtime.h>
#include <hip/hip_bf16.h>
#include <hip/hip_cooperative_groups.h>

namespace cg = cooperative_groups;

// Problem constants (from reference setup_inputs)
#define T1 4095     // existing stack entries
#define TT 4096     // T1 + 1
#define B  64
#define M  128
#define BM (B * M)                // 8192
#define ROW4 (BM / 4)             // 2048 float4 per row
#define IPB 32                    // rows per fuse chunk
#define HPB (IPB / 2)             // 16 rows per half-block
#define NCHUNK (TT / IPB)         // 128

// mega (cooperative) config: 256 blocks = 1/CU (weakest co-residency ask)
#define MT 512
#define MWAVES (MT / 64)          // 8
#define MSEPT (TT / MT)           // 8 scan elements per thread
#define MGRID 256
#define MCPB 4                    // fuse chunks per block (32 groups x 4)

// fallback scan config (round-13, proven 56.4 us)
#define FST 1024
#define FNW (FST / 64)
#define FEPT (TT / FST)           // 4

typedef float f32x4 __attribute__((ext_vector_type(4)));

// ---------------------------------------------------------------------------
// Cooperative mega-kernel: 3 phases, 2 grid.sync()s, zero extra launches.
//  P1 (blocks 0..63):  suffix-scan per batch -> snT, coeffT (transposed).
//  P2 (all 256):       round-11 fuse body, 4 chunks per block.
//  P3 (blocks 0..63):  reduce partials -> r; (64..127): snT -> sn transpose.
// ---------------------------------------------------------------------------
__global__ __launch_bounds__(MT) void mega_kernel(
    const float* __restrict__ V,        // [T1, B, M]
    const float* __restrict__ s,        // [T1, B]
    const float* __restrict__ d,        // [B]
    const float* __restrict__ u,        // [B]
    const float* __restrict__ v,        // [B, M]
    float* __restrict__ Vn,             // [TT, B, M] (output 0)
    float* __restrict__ sn_out,         // [TT, B]    (output 1)
    float* __restrict__ r,              // [B, M]     (output 2)
    float* __restrict__ coeffT,         // [B, TT]  ws
    float* __restrict__ snT,            // [B, TT]  ws
    float* __restrict__ partials)       // [NCHUNK, BM] ws
{
    cg::grid_group grid = cg::this_grid();
    const int bid = blockIdx.x;
    const int tid = threadIdx.x;

    __shared__ __align__(16) char smem[64 * 65 * 4];   // 16.6 KB, phase-unioned
    __shared__ float wtot1[MWAVES], wtot2[MWAVES];

    // ---------------- Phase 1: scan (blocks 0..63) ----------------
    if (bid < B) {
        const int b = bid;
        const int lane = tid & 63, wave = tid >> 6;
        const int base = tid * MSEPT;

        float sv[MSEPT];
        float sum = 0.f;
#pragma unroll
        for (int k = 0; k < MSEPT; ++k) {
            int i = base + k;
            float val = (i < T1) ? s[(size_t)i * B + b] : 0.f;
            sv[k] = val;
            sum += val;
        }
        float x = sum;                       // wave suffix scan (Kogge-Stone)
#pragma unroll
        for (int off = 1; off < 64; off <<= 1) {
            float y = __shfl_down(x, off);
            if (lane + off < 64) x += y;
        }
        if (lane == 0) wtot1[wave] = x;
        __syncthreads();
        float after = 0.f;
#pragma unroll
        for (int w = 0; w < MWAVES; ++w)
            if (w > wave) after += wtot1[w];
        float suffix = after + x - sum;

        const float ub = u[b];
        float tot = suffix;
        float snv[MSEPT];
#pragma unroll
        for (int k = MSEPT - 1; k >= 0; --k) {
            float sval = sv[k];
            snv[k] = fmaxf(sval - fmaxf(ub - tot, 0.f), 0.f);
            tot += sval;
        }
        if (tid == MT - 1) snv[MSEPT - 1] = d[b];   // element T1: sn = d

        float sum2 = 0.f;
#pragma unroll
        for (int k = 0; k < MSEPT; ++k) sum2 += snv[k];
        float x2 = sum2;
#pragma unroll
        for (int off = 1; off < 64; off <<= 1) {
            float y = __shfl_down(x2, off);
            if (lane + off < 64) x2 += y;
        }
        if (lane == 0) wtot2[wave] = x2;
        __syncthreads();
        float after2 = 0.f;
#pragma unroll
        for (int w = 0; w < MWAVES; ++w)
            if (w > wave) after2 += wtot2[w];
        float suffix2 = after2 + x2 - sum2;

        float tot2 = suffix2;
        float cv[MSEPT];
#pragma unroll
        for (int k = MSEPT - 1; k >= 0; --k) {
            float snval = snv[k];
            cv[k] = fminf(snval, fmaxf(1.f - tot2, 0.f));
            tot2 += snval;
        }
        f32x4* sp = (f32x4*)(snT + (size_t)b * TT + base);
        sp[0] = (f32x4){snv[0], snv[1], snv[2], snv[3]};
        sp[1] = (f32x4){snv[4], snv[5], snv[6], snv[7]};
        f32x4* cp = (f32x4*)(coeffT + (size_t)b * TT + base);
        cp[0] = (f32x4){cv[0], cv[1], cv[2], cv[3]};
        cp[1] = (f32x4){cv[4], cv[5], cv[6], cv[7]};
    }

    grid.sync();

    // ---------------- Phase 2: fuse (all blocks, 4 chunks) ----------------
    {
        const int bmTile = bid & 7;
        const int cg0 = bid >> 3;                  // 0..31
        const int half = tid >> 8;                 // 0 or 1
        const int t = tid & 255;
        const int bm4 = bmTile * 256 + t;          // float4 column
        const int b = bm4 >> 5;                    // batch
        f32x4* shc = (f32x4*)smem;                 // 256 f32x4 (4 KB)
        const f32x4* Vp  = (const f32x4*)V;
        f32x4*       Vnp = (f32x4*)Vn;
        const float* cbase = coeffT + (size_t)b * TT;

#pragma unroll
        for (int cc = 0; cc < MCPB; ++cc) {
            const int chunk = cg0 + cc * 32;       // covers 0..127
            const int i0 = chunk * IPB + half * HPB;

            float c[HPB];
            const f32x4* cp = (const f32x4*)(cbase + i0);
#pragma unroll
            for (int q = 0; q < HPB / 4; ++q) {
                f32x4 cv4 = cp[q];
                c[4*q+0] = cv4.x; c[4*q+1] = cv4.y; c[4*q+2] = cv4.z; c[4*q+3] = cv4.w;
            }

            f32x4 acc = {0.f, 0.f, 0.f, 0.f};
            const bool lastHalf = (chunk == NCHUNK - 1) && (half == 1);
            if (!lastHalf) {
#pragma unroll
                for (int k = 0; k < HPB; ++k) {
                    const size_t idx = (size_t)(i0 + k) * ROW4 + bm4;
                    f32x4 val = Vp[idx];                    // cached (L3 reuse)
                    __builtin_nontemporal_store(val, &Vnp[idx]);
                    acc += c[k] * val;
                }
            } else {
#pragma unroll
                for (int k = 0; k < HPB - 1; ++k) {
                    const size_t idx = (size_t)(i0 + k) * ROW4 + bm4;
                    f32x4 val = Vp[idx];
                    __builtin_nontemporal_store(val, &Vnp[idx]);
                    acc += c[k] * val;
                }
                f32x4 val = ((const f32x4*)v)[bm4];         // push v at i = T1
                __builtin_nontemporal_store(val, &Vnp[(size_t)T1 * ROW4 + bm4]);
                acc += c[HPB - 1] * val;
            }

            __syncthreads();                 // guard shc reuse across chunks
            if (half == 1) shc[t] = acc;
            __syncthreads();
            if (half == 0)
                ((f32x4*)partials)[(size_t)chunk * ROW4 + bm4] = acc + shc[t];
        }
    }

    grid.sync();

    // ---------------- Phase 3: finish ----------------
    if (bid < 64) {
        // reduce partials -> r (fixed order, deterministic)
        f32x4* sh512 = (f32x4*)smem;           // 512 f32x4 (8 KB)
        const int grp = tid >> 5;              // 0..15
        const int lane = tid & 31;
        const int out4 = bid * 32 + lane;      // 0..2047
        f32x4 acc = {0.f, 0.f, 0.f, 0.f};
#pragma unroll
        for (int c = grp; c < NCHUNK; c += 16)
            acc += ((const f32x4*)partials)[(size_t)c * ROW4 + out4];
        sh512[tid] = acc;
        __syncthreads();
        if (tid < 256) sh512[tid] += sh512[tid + 256];
        __syncthreads();
        if (tid < 128) sh512[tid] += sh512[tid + 128];
        __syncthreads();
        if (tid < 64) sh512[tid] += sh512[tid + 64];
        __syncthreads();
        if (tid < 32) ((f32x4*)r)[out4] = sh512[tid] + sh512[tid + 32];
    } else if (bid < 128) {
        // transpose snT [B,TT] -> sn_out [TT,B], rows [g*64, g*64+64)
        const int g = bid - 64;
        float (*tile)[65] = (float(*)[65])smem;
        {
            const int b    = tid >> 3;             // 0..63
            const int ioff = (tid & 7) * 8;        // 0..56
            const f32x4* src4 = (const f32x4*)(snT + (size_t)b * TT + g * 64 + ioff);
            f32x4 v0 = src4[0], v1 = src4[1];      // coalesced
            tile[ioff+0][b] = v0.x; tile[ioff+1][b] = v0.y;
            tile[ioff+2][b] = v0.z; tile[ioff+3][b] = v0.w;
            tile[ioff+4][b] = v1.x; tile[ioff+5][b] = v1.y;
            tile[ioff+6][b] = v1.z; tile[ioff+7][b] = v1.w;
        }
        __syncthreads();
        {
            const int i    = tid >> 3;             // 0..63
            const int boff = (tid & 7) * 8;        // 0..56
            float* dst = sn_out + (size_t)(g * 64 + i) * B + boff;
            *(f32x4*)dst = (f32x4){tile[i][boff+0], tile[i][boff+1],
                                   tile[i][boff+2], tile[i][boff+3]};
            *(f32x4*)(dst + 4) = (f32x4){tile[i][boff+4], tile[i][boff+5],
                                         tile[i][boff+6], tile[i][boff+7]};
        }
    }
}

// ---------------------------------------------------------------------------
// Fallback path: round-13 three-kernel pipeline (proven, 56.4 us).
// ---------------------------------------------------------------------------
__global__ __launch_bounds__(FST) void scan_kernel(
    const float* __restrict__ s, const float* __restrict__ d,
    const float* __restrict__ u,
    float* __restrict__ snT, float* __restrict__ coeffT)
{
    const int b = blockIdx.x;
    const int t = threadIdx.x;
    const int lane = t & 63;
    const int wave = t >> 6;
    __shared__ float wtot1[FNW], wtot2[FNW];

    const int base = t * FEPT;
    float sv[FEPT];
    float sum = 0.f;
#pragma unroll
    for (int k = 0; k < FEPT; ++k) {
        int i = base + k;
        float val = (i < T1) ? s[(size_t)i * B + b] : 0.f;
        sv[k] = val;
        sum += val;
    }
    float x = sum;
#pragma unroll
    for (int off = 1; off < 64; off <<= 1) {
        float y = __shfl_down(x, off);
        if (lane + off < 64) x += y;
    }
    if (lane == 0) wtot1[wave] = x;
    __syncthreads();
    float after = 0.f;
#pragma unroll
    for (int w = 0; w < FNW; ++w)
        if (w > wave) after += wtot1[w];
    float suffix = after + x - sum;

    const float ub = u[b];
    float tot = suffix;
    float snv[FEPT];
#pragma unroll
    for (int k = FEPT - 1; k >= 0; --k) {
        float sval = sv[k];
        snv[k] = fmaxf(sval - fmaxf(ub - tot, 0.f), 0.f);
        tot += sval;
    }
    if (t == FST - 1) snv[FEPT - 1] = d[b];

    float sum2 = 0.f;
#pragma unroll
    for (int k = 0; k < FEPT; ++k) sum2 += snv[k];
    float x2 = sum2;
#pragma unroll
    for (int off = 1; off < 64; off <<= 1) {
        float y = __shfl_down(x2, off);
        if (lane + off < 64) x2 += y;
    }
    if (lane == 0) wtot2[wave] = x2;
    __syncthreads();
    float after2 = 0.f;
#pragma unroll
    for (int w = 0; w < FNW; ++w)
        if (w > wave) after2 += wtot2[w];
    float suffix2 = after2 + x2 - sum2;

    float tot2 = suffix2;
    float cv[FEPT];
#pragma unroll
    for (int k = FEPT - 1; k >= 0; --k) {
        float snval = snv[k];
        cv[k] = fminf(snval, fmaxf(1.f - tot2, 0.f));
        tot2 += snval;
    }
    *(f32x4*)(snT + (size_t)b * TT + base) = (f32x4){snv[0], snv[1], snv[2], snv[3]};
    *(f32x4*)(coeffT + (size_t)b * TT + base) = (f32x4){cv[0], cv[1], cv[2], cv[3]};
}

__global__ __launch_bounds__(512) void fuse_kernel(
    const float* __restrict__ V, const float* __restrict__ v,
    const float* __restrict__ coeffT,
    float* __restrict__ Vn, float* __restrict__ partials)
{
    const int bmTile = blockIdx.x;
    const int chunk  = blockIdx.y;
    const int tid  = threadIdx.x;
    const int half = tid >> 8;
    const int t    = tid & 255;
    const int bm4  = bmTile * 256 + t;
    const int b    = bm4 >> 5;
    const int i0   = chunk * IPB + half * HPB;

    float c[HPB];
    const f32x4* cp = (const f32x4*)(coeffT + (size_t)b * TT + i0);
#pragma unroll
    for (int q = 0; q < HPB / 4; ++q) {
        f32x4 cc = cp[q];
        c[4*q+0] = cc.x; c[4*q+1] = cc.y; c[4*q+2] = cc.z; c[4*q+3] = cc.w;
    }

    f32x4 acc = {0.f, 0.f, 0.f, 0.f};
    const f32x4* Vp  = (const f32x4*)V;
    f32x4*       Vnp = (f32x4*)Vn;

    const bool lastHalf = (chunk == NCHUNK - 1) && (half == 1);
    if (!lastHalf) {
#pragma unroll
        for (int k = 0; k < HPB; ++k) {
            const size_t idx = (size_t)(i0 + k) * ROW4 + bm4;
            f32x4 val = Vp[idx];
            __builtin_nontemporal_store(val, &Vnp[idx]);
            acc += c[k] * val;
        }
    } else {
#pragma unroll
        for (int k = 0; k < HPB - 1; ++k) {
            const size_t idx = (size_t)(i0 + k) * ROW4 + bm4;
            f32x4 val = Vp[idx];
            __builtin_nontemporal_store(val, &Vnp[idx]);
            acc += c[k] * val;
        }
        f32x4 val = ((const f32x4*)v)[bm4];
        __builtin_nontemporal_store(val, &Vnp[(size_t)T1 * ROW4 + bm4]);
        acc += c[HPB - 1] * val;
    }

    __shared__ f32x4 sh[256];
    if (half == 1) sh[t] = acc;
    __syncthreads();
    if (half == 0)
        ((f32x4*)partials)[(size_t)chunk * ROW4 + bm4] = acc + sh[t];
}

__global__ __launch_bounds__(256) void finish_kernel(
    const float* __restrict__ partials, const float* __restrict__ snT,
    float* __restrict__ r, float* __restrict__ sn_out)
{
    const int blk = blockIdx.x;
    const int tid = threadIdx.x;

    if (blk < 64) {
        const int grp = tid >> 5;
        const int lane = tid & 31;
        const int out4 = blk * 32 + lane;

        f32x4 acc = {0.f, 0.f, 0.f, 0.f};
#pragma unroll 8
        for (int c = grp; c < NCHUNK; c += 8)
            acc += ((const f32x4*)partials)[(size_t)c * ROW4 + out4];

        __shared__ f32x4 sh[256];
        sh[tid] = acc;
        __syncthreads();
        if (tid < 128) sh[tid] += sh[tid + 128];
        __syncthreads();
        if (tid < 64) sh[tid] += sh[tid + 64];
        __syncthreads();
        if (tid < 32) ((f32x4*)r)[out4] = sh[tid] + sh[tid + 32];
    } else {
        const int g = blk - 64;
        __shared__ float tile[64][65];

        const int b  = tid >> 2;
        const int iq = tid & 3;
        const f32x4* src4 = (const f32x4*)(snT + (size_t)b * TT + g * 64 + iq * 16);
#pragma unroll
        for (int q = 0; q < 4; ++q) {
            f32x4 vv = src4[q];
            tile[iq * 16 + q * 4 + 0][b] = vv.x;
            tile[iq * 16 + q * 4 + 1][b] = vv.y;
            tile[iq * 16 + q * 4 + 2][b] = vv.z;
            tile[iq * 16 + q * 4 + 3][b] = vv.w;
        }
        __syncthreads();

        const int il = tid >> 6;
        const int bb = tid & 63;
#pragma unroll
        for (int p = 0; p < 16; ++p) {
            const int i = p * 4 + il;
            sn_out[(size_t)(g * 64 + i) * B + bb] = tile[i][bb];
        }
    }
}

extern "C" void kernel_launch(void* const* d_in, const int* in_sizes, int n_in,
                              void* d_out, int out_size, void* d_ws, size_t ws_size,
                              hipStream_t stream) {
    const float* V = (const float*)d_in[0];   // [T1,B,M]
    const float* s = (const float*)d_in[1];   // [T1,B,1]
    const float* d = (const float*)d_in[2];   // [B,1]
    const float* u = (const float*)d_in[3];   // [B,1]
    const float* v = (const float*)d_in[4];   // [B,M]

    float* out = (float*)d_out;
    float* Vn = out;                                   // TT*B*M
    float* sn = out + (size_t)TT * BM;                 // TT*B
    float* r  = sn + (size_t)TT * B;                   // B*M

    float* coeffT   = (float*)d_ws;                    // B*TT floats (1 MB)
    float* snT      = coeffT + (size_t)B * TT;         // B*TT floats (1 MB)
    float* partials = snT + (size_t)B * TT;            // NCHUNK*BM floats (4 MB)

    // Deterministic host-side capability check (no stream ops; capture-safe).
    int dev = 0;
    (void)hipGetDevice(&dev);
    int coopOK = 0;
    (void)hipDeviceGetAttribute(&coopOK, hipDeviceAttributeCooperativeLaunch, dev);
    int numCU = 0;
    (void)hipDeviceGetAttribute(&numCU, hipDeviceAttributeMultiprocessorCount, dev);
    int maxBpc = 0;
    hipError_t qe = hipOccupancyMaxActiveBlocksPerMultiprocessor(
        &maxBpc, (const void*)mega_kernel, MT, 0);

    bool done = false;
    if (coopOK && qe == hipSuccess && (long)maxBpc * numCU >= MGRID) {
        void* args[] = {
            (void*)&V, (void*)&s, (void*)&d, (void*)&u, (void*)&v,
            (void*)&Vn, (void*)&sn, (void*)&r,
            (void*)&coeffT, (void*)&snT, (void*)&partials
        };
        hipError_t e = hipLaunchCooperativeKernel((const void*)mega_kernel,
                                                  dim3(MGRID), dim3(MT),
                                                  args, 0, stream);
        if (e == hipSuccess) done = true;
        else (void)hipGetLastError();   // clear sticky error, use fallback
    }
    if (!done) {
        scan_kernel<<<B, FST, 0, stream>>>(s, d, u, snT, coeffT);
        fuse_kernel<<<dim3(8, NCHUNK), 512, 0, stream>>>(V, v, coeffT, Vn, partials);
        finish_kernel<<<128, 256, 0, stream>>>(partials, snT, r, sn);
    }
}

// Round 16
// 60.425 us; speedup vs baseline: 2.1896x; 2.1896x over previous
//
#include <hip/hip_runtime.h>
#include <hip/hip_bf16.h>

// Problem constants (from reference setup_inputs)
#define T1 4095     // existing stack entries
#define TT 4096     // T1 + 1
#define B  64
#define M  128
#define BM (B * M)                // 8192
#define ROW4 (BM / 4)             // 2048 float4 per row
#define SCAN_THREADS 1024
#define NWAVE (SCAN_THREADS / 64) // 16 waves
#define EPT (TT / SCAN_THREADS)   // 4 elements per thread in scan
#define IPB 32                    // rows per fuse chunk
#define HPB (IPB / 2)             // 16 rows per half-block
#define NCHUNK (TT / IPB)         // 128

typedef float f32x4 __attribute__((ext_vector_type(4)));

// Kernel 1 (round-13, proven): per batch b, 1024 threads:
//   sn[i] = relu(s[i] - relu(u - suffix_s[i])), sn[T1] = d
//   coeff[i] = min(sn[i], relu(1 - suffix_sn[i]))
// Both outputs TRANSPOSED [B,TT] (coalesced float4; no scattered-4B RMW).
__global__ __launch_bounds__(SCAN_THREADS) void scan_kernel(
    const float* __restrict__ s,    // [T1, B]
    const float* __restrict__ d,    // [B]
    const float* __restrict__ u,    // [B]
    float* __restrict__ snT,        // [B, TT]  (workspace)
    float* __restrict__ coeffT)     // [B, TT]  (workspace)
{
    const int b = blockIdx.x;
    const int t = threadIdx.x;
    const int lane = t & 63;
    const int wave = t >> 6;        // 0..15
    __shared__ float wtot1[NWAVE], wtot2[NWAVE];

    const int base = t * EPT;
    float sv[EPT];
    float sum = 0.f;
#pragma unroll
    for (int k = 0; k < EPT; ++k) {
        int i = base + k;
        float val = (i < T1) ? s[(size_t)i * B + b] : 0.f;
        sv[k] = val;
        sum += val;
    }
    float x = sum;                  // wave-level suffix scan (Kogge-Stone)
#pragma unroll
    for (int off = 1; off < 64; off <<= 1) {
        float y = __shfl_down(x, off);
        if (lane + off < 64) x += y;
    }
    if (lane == 0) wtot1[wave] = x;
    __syncthreads();
    float after = 0.f;
#pragma unroll
    for (int w = 0; w < NWAVE; ++w)
        if (w > wave) after += wtot1[w];
    float suffix = after + x - sum;

    const float ub = u[b];
    float tot = suffix;
    float snv[EPT];
#pragma unroll
    for (int k = EPT - 1; k >= 0; --k) {
        float sval = sv[k];
        snv[k] = fmaxf(sval - fmaxf(ub - tot, 0.f), 0.f);
        tot += sval;
    }
    if (t == SCAN_THREADS - 1) snv[EPT - 1] = d[b];  // element T1: sn = d

    float sum2 = 0.f;
#pragma unroll
    for (int k = 0; k < EPT; ++k) sum2 += snv[k];
    float x2 = sum2;
#pragma unroll
    for (int off = 1; off < 64; off <<= 1) {
        float y = __shfl_down(x2, off);
        if (lane + off < 64) x2 += y;
    }
    if (lane == 0) wtot2[wave] = x2;
    __syncthreads();
    float after2 = 0.f;
#pragma unroll
    for (int w = 0; w < NWAVE; ++w)
        if (w > wave) after2 += wtot2[w];
    float suffix2 = after2 + x2 - sum2;

    float tot2 = suffix2;
    float cv[EPT];
#pragma unroll
    for (int k = EPT - 1; k >= 0; --k) {
        float snval = snv[k];
        cv[k] = fminf(snval, fmaxf(1.f - tot2, 0.f));
        tot2 += snval;
    }
    *(f32x4*)(snT + (size_t)b * TT + base) = (f32x4){snv[0], snv[1], snv[2], snv[3]};
    *(f32x4*)(coeffT + (size_t)b * TT + base) = (f32x4){cv[0], cv[1], cv[2], cv[3]};
}

// Kernel 2: fused Vn copy + coeff-weighted partial reduction, PLUS the
// snT->sn transpose folded in as 8 extra blocks (chunk index == NCHUNK).
// Transpose depends only on scan, so it runs in the shadow of the 1024
// streaming blocks instead of serialized in the finish tail.
// Streaming body is round-13/11 verbatim (best measured).
__global__ __launch_bounds__(512) void fuse_kernel(
    const float* __restrict__ V,        // [T1, B, M]
    const float* __restrict__ v,        // [B, M]
    const float* __restrict__ coeffT,   // [B, TT]
    const float* __restrict__ snT,      // [B, TT]
    float* __restrict__ Vn,             // [TT, B, M] (output 0)
    float* __restrict__ sn_out,         // [TT, B]    (output 1)
    float* __restrict__ partials)       // [NCHUNK, BM]
{
    const int bmTile = blockIdx.x;                   // 0..7
    const int chunk  = blockIdx.y;                   // 0..128
    const int tid  = threadIdx.x;                    // 0..511

    __shared__ __align__(16) float smem[64 * 65];    // 16.6 KB (union)

    if (chunk == NCHUNK) {
        // ---- transpose blocks: 8 row-group tiles each ----
        float (*tile)[65] = (float(*)[65])smem;
#pragma unroll 1
        for (int j = 0; j < 8; ++j) {
            const int g = bmTile * 8 + j;            // 0..63; rows [g*64, g*64+64)
            {
                const int b    = tid >> 3;           // 0..63
                const int ioff = (tid & 7) * 8;      // 0..56
                const f32x4* src4 = (const f32x4*)(snT + (size_t)b * TT + g * 64 + ioff);
                f32x4 v0 = src4[0], v1 = src4[1];    // coalesced
                tile[ioff+0][b] = v0.x; tile[ioff+1][b] = v0.y;
                tile[ioff+2][b] = v0.z; tile[ioff+3][b] = v0.w;
                tile[ioff+4][b] = v1.x; tile[ioff+5][b] = v1.y;
                tile[ioff+6][b] = v1.z; tile[ioff+7][b] = v1.w;
            }
            __syncthreads();
            {
                const int i    = tid >> 3;           // 0..63
                const int boff = (tid & 7) * 8;      // 0..56
                float* dst = sn_out + (size_t)(g * 64 + i) * B + boff;
                *(f32x4*)dst = (f32x4){tile[i][boff+0], tile[i][boff+1],
                                       tile[i][boff+2], tile[i][boff+3]};
                *(f32x4*)(dst + 4) = (f32x4){tile[i][boff+4], tile[i][boff+5],
                                             tile[i][boff+6], tile[i][boff+7]};
            }
            __syncthreads();
        }
        return;
    }

    // ---- streaming blocks (round-13 fuse body) ----
    const int half = tid >> 8;                       // 0 or 1
    const int t    = tid & 255;
    const int bm4  = bmTile * 256 + t;               // float4 column
    const int b    = bm4 >> 5;                       // batch (32 f4 per batch)
    const int i0   = chunk * IPB + half * HPB;       // 16 rows per half

    float c[HPB];
    const f32x4* cp = (const f32x4*)(coeffT + (size_t)b * TT + i0);
#pragma unroll
    for (int q = 0; q < HPB / 4; ++q) {
        f32x4 cc = cp[q];
        c[4*q+0] = cc.x; c[4*q+1] = cc.y; c[4*q+2] = cc.z; c[4*q+3] = cc.w;
    }

    f32x4 acc = {0.f, 0.f, 0.f, 0.f};
    const f32x4* Vp  = (const f32x4*)V;
    f32x4*       Vnp = (f32x4*)Vn;

    const bool lastHalf = (chunk == NCHUNK - 1) && (half == 1);
    if (!lastHalf) {
#pragma unroll
        for (int k = 0; k < HPB; ++k) {
            const size_t idx = (size_t)(i0 + k) * ROW4 + bm4;
            f32x4 val = Vp[idx];                     // cached read (L3 reuse)
            __builtin_nontemporal_store(val, &Vnp[idx]);
            acc += c[k] * val;
        }
    } else {
#pragma unroll
        for (int k = 0; k < HPB - 1; ++k) {
            const size_t idx = (size_t)(i0 + k) * ROW4 + bm4;
            f32x4 val = Vp[idx];
            __builtin_nontemporal_store(val, &Vnp[idx]);
            acc += c[k] * val;
        }
        f32x4 val = ((const f32x4*)v)[bm4];          // push v at i = T1
        __builtin_nontemporal_store(val, &Vnp[(size_t)T1 * ROW4 + bm4]);
        acc += c[HPB - 1] * val;
    }

    f32x4* shc = (f32x4*)smem;                       // 4 KB of the union
    if (half == 1) shc[t] = acc;
    __syncthreads();
    if (half == 0)
        ((f32x4*)partials)[(size_t)chunk * ROW4 + bm4] = acc + shc[t];
}

// Kernel 3: reduce only (64 blocks x 256 threads), deterministic fixed order.
__global__ __launch_bounds__(256) void finish_kernel(
    const float* __restrict__ partials,  // [NCHUNK, BM]
    float* __restrict__ r)               // [B, M] (output 2)
{
    const int blk = blockIdx.x;          // 0..63
    const int tid = threadIdx.x;
    const int grp = tid >> 5;            // 0..7
    const int lane = tid & 31;
    const int out4 = blk * 32 + lane;    // float4 output index 0..2047

    f32x4 acc = {0.f, 0.f, 0.f, 0.f};
#pragma unroll 8
    for (int c = grp; c < NCHUNK; c += 8)
        acc += ((const f32x4*)partials)[(size_t)c * ROW4 + out4];

    __shared__ f32x4 sh[256];
    sh[tid] = acc;
    __syncthreads();
    if (tid < 128) sh[tid] += sh[tid + 128];
    __syncthreads();
    if (tid < 64) sh[tid] += sh[tid + 64];
    __syncthreads();
    if (tid < 32) ((f32x4*)r)[out4] = sh[tid] + sh[tid + 32];
}

extern "C" void kernel_launch(void* const* d_in, const int* in_sizes, int n_in,
                              void* d_out, int out_size, void* d_ws, size_t ws_size,
                              hipStream_t stream) {
    const float* V = (const float*)d_in[0];   // [T1,B,M]
    const float* s = (const float*)d_in[1];   // [T1,B,1]
    const float* d = (const float*)d_in[2];   // [B,1]
    const float* u = (const float*)d_in[3];   // [B,1]
    const float* v = (const float*)d_in[4];   // [B,M]

    float* out = (float*)d_out;
    float* Vn = out;                                   // TT*B*M
    float* sn = out + (size_t)TT * BM;                 // TT*B
    float* r  = sn + (size_t)TT * B;                   // B*M

    float* coeffT   = (float*)d_ws;                    // B*TT floats (1 MB)
    float* snT      = coeffT + (size_t)B * TT;         // B*TT floats (1 MB)
    float* partials = snT + (size_t)B * TT;            // NCHUNK*BM floats (4 MB)

    scan_kernel<<<B, SCAN_THREADS, 0, stream>>>(s, d, u, snT, coeffT);
    fuse_kernel<<<dim3(8, NCHUNK + 1), 512, 0, stream>>>(V, v, coeffT, snT,
                                                         Vn, sn, partials);
    finish_kernel<<<64, 256, 0, stream>>>(partials, r);
}

// Round 17
// 56.451 us; speedup vs baseline: 2.3437x; 1.0704x over previous
//
#include <hip/hip_runtime.h>
#include <hip/hip_bf16.h>

// Problem constants (from reference setup_inputs)
#define T1 4095     // existing stack entries
#define TT 4096     // T1 + 1
#define B  64
#define M  128
#define BM (B * M)                // 8192
#define ROW4 (BM / 4)             // 2048 float4 per row
#define SCAN_THREADS 1024
#define NWAVE (SCAN_THREADS / 64) // 16 waves
#define EPT (TT / SCAN_THREADS)   // 4 elements per thread in scan
#define IPB 32                    // rows per fuse chunk
#define HPB (IPB / 2)             // 16 rows per half-block
#define NCHUNK (TT / IPB)         // 128

typedef float f32x4 __attribute__((ext_vector_type(4)));

// Kernel 1: per batch b (one block per b), 1024 threads (16 waves):
//   sn[i] = relu(s[i] - relu(u - suffix_s[i])), sn[T1] = d
//   coeff[i] = min(sn[i], relu(1 - suffix_sn[i]))
// BOTH outputs written TRANSPOSED [B,TT] (fully coalesced float4) — the
// strided [TT,B] sn write was a scattered-4B cross-XCD RMW (r13 fix, -3 us).
__global__ __launch_bounds__(SCAN_THREADS) void scan_kernel(
    const float* __restrict__ s,    // [T1, B]
    const float* __restrict__ d,    // [B]
    const float* __restrict__ u,    // [B]
    float* __restrict__ snT,        // [B, TT]  (workspace, transposed)
    float* __restrict__ coeffT)     // [B, TT]  (workspace, transposed)
{
    const int b = blockIdx.x;
    const int t = threadIdx.x;
    const int lane = t & 63;
    const int wave = t >> 6;        // 0..15
    __shared__ float wtot1[NWAVE];
    __shared__ float wtot2[NWAVE];

    const int base = t * EPT;
    float sv[EPT];
    float sum = 0.f;
#pragma unroll
    for (int k = 0; k < EPT; ++k) {
        int i = base + k;
        float val = (i < T1) ? s[(size_t)i * B + b] : 0.f;
        sv[k] = val;
        sum += val;
    }

    // Wave-level inclusive suffix scan (Kogge-Stone, high-to-low).
    float x = sum;
#pragma unroll
    for (int off = 1; off < 64; off <<= 1) {
        float y = __shfl_down(x, off);
        if (lane + off < 64) x += y;
    }
    if (lane == 0) wtot1[wave] = x;          // wave total
    __syncthreads();
    float after = 0.f;
#pragma unroll
    for (int w = 0; w < NWAVE; ++w)
        if (w > wave) after += wtot1[w];
    float suffix = after + x - sum;          // exclusive suffix for this thread

    const float ub = u[b];
    float tot = suffix;
    float snv[EPT];
#pragma unroll
    for (int k = EPT - 1; k >= 0; --k) {
        float sval = sv[k];
        snv[k] = fmaxf(sval - fmaxf(ub - tot, 0.f), 0.f);
        tot += sval;
    }
    if (t == SCAN_THREADS - 1) snv[EPT - 1] = d[b];  // element T1: sn = d

    float sum2 = 0.f;
#pragma unroll
    for (int k = 0; k < EPT; ++k) sum2 += snv[k];
    float x2 = sum2;
#pragma unroll
    for (int off = 1; off < 64; off <<= 1) {
        float y = __shfl_down(x2, off);
        if (lane + off < 64) x2 += y;
    }
    if (lane == 0) wtot2[wave] = x2;
    __syncthreads();
    float after2 = 0.f;
#pragma unroll
    for (int w = 0; w < NWAVE; ++w)
        if (w > wave) after2 += wtot2[w];
    float suffix2 = after2 + x2 - sum2;

    float tot2 = suffix2;
    float cv[EPT];
#pragma unroll
    for (int k = EPT - 1; k >= 0; --k) {
        float snval = snv[k];
        cv[k] = fminf(snval, fmaxf(1.f - tot2, 0.f));
        tot2 += snval;
    }
    f32x4 sv4 = { snv[0], snv[1], snv[2], snv[3] };
    *(f32x4*)(snT + (size_t)b * TT + base) = sv4;     // coalesced float4
    f32x4 cc = { cv[0], cv[1], cv[2], cv[3] };
    *(f32x4*)(coeffT + (size_t)b * TT + base) = cc;   // coalesced float4
}

// Kernel 2: fused Vn copy + coeff-weighted partial reduction.
// Best-measured config (r11/r13): strip layout (8 bmTiles, 128 chunks),
// 512-thread blocks (32 waves/CU); half 0 -> rows [i0,i0+16), half 1 ->
// [i0+16,i0+32); halves combined via LDS. Cached V loads (L3 serves ~half
// across graph replays); NT stores for Vn (A/B-proven vs plain, r8).
__global__ __launch_bounds__(512) void fuse_kernel(
    const float* __restrict__ V,        // [T1, B, M]
    const float* __restrict__ v,        // [B, M]
    const float* __restrict__ coeffT,   // [B, TT]
    float* __restrict__ Vn,             // [TT, B, M] (output 0)
    float* __restrict__ partials)       // [NCHUNK, BM]
{
    const int bmTile = blockIdx.x;                   // 0..7
    const int chunk  = blockIdx.y;                   // 0..127
    const int tid  = threadIdx.x;                    // 0..511
    const int half = tid >> 8;                       // 0 or 1
    const int t    = tid & 255;
    const int bm4  = bmTile * 256 + t;               // float4 column
    const int b    = bm4 >> 5;                       // batch (32 f4 per batch)
    const int i0   = chunk * IPB + half * HPB;       // 16 rows per half

    // Preload this half's 16 coefficients (contiguous in coeffT).
    float c[HPB];
    const f32x4* cp = (const f32x4*)(coeffT + (size_t)b * TT + i0);
#pragma unroll
    for (int q = 0; q < HPB / 4; ++q) {
        f32x4 cc = cp[q];
        c[4*q+0] = cc.x; c[4*q+1] = cc.y; c[4*q+2] = cc.z; c[4*q+3] = cc.w;
    }

    f32x4 acc = {0.f, 0.f, 0.f, 0.f};
    const f32x4* Vp  = (const f32x4*)V;
    f32x4*       Vnp = (f32x4*)Vn;

    const bool lastHalf = (chunk == NCHUNK - 1) && (half == 1);
    if (!lastHalf) {
#pragma unroll
        for (int k = 0; k < HPB; ++k) {
            const size_t idx = (size_t)(i0 + k) * ROW4 + bm4;
            f32x4 val = Vp[idx];                       // cached read (L3 reuse)
            __builtin_nontemporal_store(val, &Vnp[idx]);
            acc += c[k] * val;
        }
    } else {
#pragma unroll
        for (int k = 0; k < HPB - 1; ++k) {
            const size_t idx = (size_t)(i0 + k) * ROW4 + bm4;
            f32x4 val = Vp[idx];
            __builtin_nontemporal_store(val, &Vnp[idx]);
            acc += c[k] * val;
        }
        f32x4 val = ((const f32x4*)v)[bm4];            // push v at i = T1
        __builtin_nontemporal_store(val, &Vnp[(size_t)T1 * ROW4 + bm4]);
        acc += c[HPB - 1] * val;
    }

    // Combine the two halves (4 KB LDS, one barrier), then store partial.
    __shared__ f32x4 sh[256];
    if (half == 1) sh[t] = acc;
    __syncthreads();
    if (half == 0)
        ((f32x4*)partials)[(size_t)chunk * ROW4 + bm4] = acc + sh[t];
}

// Kernel 3 (merged finish): blocks 0..63 reduce partials -> r; blocks
// 64..127 transpose snT [B,TT] -> sn [TT,B] via LDS tile (coalesced reads
// AND writes; full 256B lines per row).
__global__ __launch_bounds__(256) void finish_kernel(
    const float* __restrict__ partials,  // [NCHUNK, BM]
    const float* __restrict__ snT,       // [B, TT]
    float* __restrict__ r,               // [B, M] (output 2)
    float* __restrict__ sn_out)          // [TT, B] (output 1)
{
    const int blk = blockIdx.x;
    const int tid = threadIdx.x;

    if (blk < 64) {
        // ---- reduce ----
        const int grp = tid >> 5;            // 0..7
        const int lane = tid & 31;
        const int out4 = blk * 32 + lane;    // float4 output index 0..2047

        f32x4 acc = {0.f, 0.f, 0.f, 0.f};
#pragma unroll 8
        for (int c = grp; c < NCHUNK; c += 8)
            acc += ((const f32x4*)partials)[(size_t)c * ROW4 + out4];

        __shared__ f32x4 sh[256];
        sh[tid] = acc;
        __syncthreads();
        if (tid < 128) sh[tid] += sh[tid + 128];
        __syncthreads();
        if (tid < 64) sh[tid] += sh[tid + 64];
        __syncthreads();
        if (tid < 32) {
            f32x4 res = sh[tid] + sh[tid + 32];
            ((f32x4*)r)[out4] = res;
        }
    } else {
        // ---- transpose snT -> sn_out, 64 i-rows per block ----
        const int g = blk - 64;              // 0..63; rows [g*64, g*64+64)
        __shared__ float tile[64][65];       // +1 pad vs bank conflicts

        const int b  = tid >> 2;             // 0..63
        const int iq = tid & 3;              // 0..3 (16 i's each)
        const f32x4* src4 = (const f32x4*)(snT + (size_t)b * TT + g * 64 + iq * 16);
#pragma unroll
        for (int q = 0; q < 4; ++q) {
            f32x4 vv = src4[q];              // coalesced read
            tile[iq * 16 + q * 4 + 0][b] = vv.x;
            tile[iq * 16 + q * 4 + 1][b] = vv.y;
            tile[iq * 16 + q * 4 + 2][b] = vv.z;
            tile[iq * 16 + q * 4 + 3][b] = vv.w;
        }
        __syncthreads();

        const int il = tid >> 6;             // 0..3
        const int bb = tid & 63;             // 0..63
#pragma unroll
        for (int p = 0; p < 16; ++p) {
            const int i = p * 4 + il;
            sn_out[(size_t)(g * 64 + i) * B + bb] = tile[i][bb];  // full-line write
        }
    }
}

extern "C" void kernel_launch(void* const* d_in, const int* in_sizes, int n_in,
                              void* d_out, int out_size, void* d_ws, size_t ws_size,
                              hipStream_t stream) {
    const float* V = (const float*)d_in[0];   // [T1,B,M]
    const float* s = (const float*)d_in[1];   // [T1,B,1]
    const float* d = (const float*)d_in[2];   // [B,1]
    const float* u = (const float*)d_in[3];   // [B,1]
    const float* v = (const float*)d_in[4];   // [B,M]

    float* out = (float*)d_out;
    float* Vn = out;                                   // TT*B*M
    float* sn = out + (size_t)TT * BM;                 // TT*B
    float* r  = sn + (size_t)TT * B;                   // B*M

    float* coeffT   = (float*)d_ws;                    // B*TT floats (1 MB)
    float* snT      = coeffT + (size_t)B * TT;         // B*TT floats (1 MB)
    float* partials = snT + (size_t)B * TT;            // NCHUNK*BM floats (4 MB)

    scan_kernel<<<B, SCAN_THREADS, 0, stream>>>(s, d, u, snT, coeffT);
    fuse_kernel<<<dim3(8, NCHUNK), 512, 0, stream>>>(V, v, coeffT, Vn, partials);
    finish_kernel<<<128, 256, 0, stream>>>(partials, snT, r, sn);
}